// Round 3
// baseline (386.189 us; speedup 1.0000x reference)
//
#include <hip/hip_runtime.h>
#include <hip/hip_bf16.h>

// SpikingSelfAttention: T=4 B=32 C=384 N=256 NH=8 D=48
#define T_  4
#define B_  32
#define C_  384
#define N_  256
#define NH_ 8
#define D_  48
#define HEADELE (N_*D_)      // 12288 elements per (t,b,h)

typedef __attribute__((ext_vector_type(8))) short bf16x8;
typedef __attribute__((ext_vector_type(4))) float f32x4;

__device__ __forceinline__ float bf2f(unsigned short s) {
    return __uint_as_float(((unsigned int)s) << 16);
}
__device__ __forceinline__ unsigned short f2bf(float f) {
    __hip_bfloat16 h = __float2bfloat16(f);
    return __builtin_bit_cast(unsigned short, h);
}
__device__ __forceinline__ void unpack8(uint4 u, float* d) {
    d[0]=__uint_as_float((u.x&0xFFFFu)<<16); d[1]=__uint_as_float(u.x&0xFFFF0000u);
    d[2]=__uint_as_float((u.y&0xFFFFu)<<16); d[3]=__uint_as_float(u.y&0xFFFF0000u);
    d[4]=__uint_as_float((u.z&0xFFFFu)<<16); d[5]=__uint_as_float(u.z&0xFFFF0000u);
    d[6]=__uint_as_float((u.w&0xFFFFu)<<16); d[7]=__uint_as_float(u.w&0xFFFF0000u);
}

// ---------------- K0: split fp32 weights into hi/lo bf16 (q,k,v,proj) ----------------
__global__ __launch_bounds__(256) void k_wsplit(const float* __restrict__ w0,
                                                const float* __restrict__ w1,
                                                const float* __restrict__ w2,
                                                const float* __restrict__ w3,
                                                unsigned short* __restrict__ hi,
                                                unsigned short* __restrict__ lo) {
    const float* w = (blockIdx.y==0) ? w0 : (blockIdx.y==1) ? w1 : (blockIdx.y==2) ? w2 : w3;
    int i = (blockIdx.x*256 + threadIdx.x)*4;       // 144 blocks * 256 * 4 = 147456
    float4 f = *(const float4*)(w + i);
    ushort4 h, l;
    h.x=f2bf(f.x); l.x=f2bf(f.x - bf2f(h.x));
    h.y=f2bf(f.y); l.y=f2bf(f.y - bf2f(h.y));
    h.z=f2bf(f.z); l.z=f2bf(f.z - bf2f(h.z));
    h.w=f2bf(f.w); l.w=f2bf(f.w - bf2f(h.w));
    size_t o = (size_t)blockIdx.y*147456 + i;
    *(ushort4*)(hi + o) = h;
    *(ushort4*)(lo + o) = l;
}

// ---------------- K1: LIF over T on x; write spikes bf16 in [T][B][N][C] ----------------
__global__ __launch_bounds__(256) void k_lif1(const float* __restrict__ x,
                                              unsigned short* __restrict__ s0) {
    __shared__ unsigned short Tt[64*72];            // [n_local][c_local], padded row 72
    const int tid = threadIdx.x;
    const int b  = blockIdx.x;
    const int c0 = blockIdx.y * 64;
    const int n0 = blockIdx.z * 64;
    const int ci = tid >> 2;
    const int nj = (tid & 3) * 16;
    float v[16];
    #pragma unroll
    for (int i=0;i<16;++i) v[i]=0.f;
    for (int t = 0; t < T_; ++t) {
        const float* xp = x + (((size_t)t*B_ + b)*C_ + c0 + ci)*N_ + n0 + nj;
        #pragma unroll
        for (int q=0;q<4;++q) {
            float4 f = *(const float4*)(xp + q*4);
            float e[4] = {f.x,f.y,f.z,f.w};
            #pragma unroll
            for (int j=0;j<4;++j) {
                int ii = q*4+j;
                float h = v[ii] + (e[j] - v[ii])*0.5f;
                bool sp = (h - 1.0f) >= 0.f;
                v[ii] = sp ? 0.f : h;
                Tt[(nj + ii)*72 + ci] = sp ? 0x3F80u : 0u;
            }
        }
        __syncthreads();
        int nrow = tid >> 2, cch = (tid & 3)*16;
        uint4 u0 = *(const uint4*)&Tt[nrow*72 + cch];
        uint4 u1 = *(const uint4*)&Tt[nrow*72 + cch + 8];
        unsigned short* gp = s0 + ((size_t)(t*B_ + b)*N_ + n0 + nrow)*C_ + c0 + cch;
        *(uint4*)gp = u0;
        *(uint4*)(gp + 8) = u1;
        __syncthreads();
    }
}

// ------------- K2: MFMA branch GEMM (Whi+Wlo) @ S + BN + LIF, LDS-free K-loop -------------
struct Br2 {
    const unsigned short* whi[3];
    const unsigned short* wlo[3];
    const float *g[3], *be[3], *me[3], *va[3];
    __hip_bfloat16* out[3];
};

__global__ __launch_bounds__(256) void k_branch(const unsigned short* __restrict__ s0, Br2 a) {
    __shared__ float Ep[32*132];
    __shared__ float BNi[128], BNo[128];
    const int tid = threadIdx.x;
    const int z  = blockIdx.z;
    const int o0 = blockIdx.x * 128;
    const int b  = blockIdx.y >> 3;
    const int n0 = (blockIdx.y & 7) * 32;
    const int w    = tid >> 6;
    const int lane = tid & 63;
    const int quad = lane >> 4;
    const int lc   = lane & 15;
    const int mbase = (w >> 1) * 64;
    const int nbase = (w & 1) * 64;
    const unsigned short* __restrict__ Wgh = a.whi[z];
    const unsigned short* __restrict__ Wgl = a.wlo[z];

    if (tid < 128) {
        int o = o0 + tid;
        float inv = a.g[z][o] / sqrtf(a.va[z][o] + 1e-5f);
        BNi[tid] = inv;
        BNo[tid] = a.be[z][o] - a.me[z][o]*inv;
    }

    // per-lane global fragment pointers (advance by 32 elements per K-step)
    const unsigned short* pAh[4];
    const unsigned short* pAl[4];
    const unsigned short* pB[4];
    #pragma unroll
    for (int mt=0;mt<4;++mt) {
        size_t off = (size_t)(o0 + mbase + mt*16 + lc)*C_ + quad*8;
        pAh[mt] = Wgh + off;
        pAl[mt] = Wgl + off;
    }
    #pragma unroll
    for (int nt=0;nt<4;++nt) {
        int col = nbase + nt*16 + lc;
        int t = col >> 5, ns = col & 31;
        pB[nt] = s0 + ((size_t)(t*B_ + b)*N_ + n0 + ns)*C_ + quad*8;
    }

    f32x4 acc[4][4];
    #pragma unroll
    for (int mt=0;mt<4;++mt)
        #pragma unroll
        for (int nt=0;nt<4;++nt) { acc[mt][nt][0]=0.f; acc[mt][nt][1]=0.f; acc[mt][nt][2]=0.f; acc[mt][nt][3]=0.f; }

    #pragma unroll 2
    for (int ks = 0; ks < 12; ++ks) {
        bf16x8 ah[4], al[4], bb[4];
        #pragma unroll
        for (int mt=0;mt<4;++mt) {
            ah[mt] = *(const bf16x8*)(pAh[mt]);
            al[mt] = *(const bf16x8*)(pAl[mt]);
            pAh[mt] += 32; pAl[mt] += 32;
        }
        #pragma unroll
        for (int nt=0;nt<4;++nt) {
            bb[nt] = *(const bf16x8*)(pB[nt]);
            pB[nt] += 32;
        }
        #pragma unroll
        for (int mt=0;mt<4;++mt)
            #pragma unroll
            for (int nt=0;nt<4;++nt) {
                acc[mt][nt] = __builtin_amdgcn_mfma_f32_16x16x32_bf16(ah[mt], bb[nt], acc[mt][nt], 0,0,0);
                acc[mt][nt] = __builtin_amdgcn_mfma_f32_16x16x32_bf16(al[mt], bb[nt], acc[mt][nt], 0,0,0);
            }
    }

    // epilogue: 4 rounds; vectorized 8-wide spike stores
    __hip_bfloat16* out = a.out[z];
    for (int r = 0; r < 4; ++r) {
        __syncthreads();
        int erow = (w>>1)*16 + quad*4;
        #pragma unroll
        for (int nt=0;nt<4;++nt) {
            int col = (w&1)*64 + nt*16 + lc;
            Ep[(erow+0)*132 + col] = acc[r][nt][0];
            Ep[(erow+1)*132 + col] = acc[r][nt][1];
            Ep[(erow+2)*132 + col] = acc[r][nt][2];
            Ep[(erow+3)*132 + col] = acc[r][nt][3];
        }
        __syncthreads();
        if (tid < 128) {
            int ns = tid & 31, oct = tid >> 5;       // 0..3
            int orow0 = oct*8;
            int oloc0 = ((orow0 & 16) ? 64 : 0) + r*16 + (orow0 & 15);
            int og = o0 + oloc0;                     // 8 consecutive o, no 48-boundary cross
            int hh = og / D_, dd0 = og - hh*D_;
            int n = n0 + ns;
            float v[8];
            #pragma unroll
            for (int j=0;j<8;++j) v[j]=0.f;
            #pragma unroll
            for (int t=0;t<4;++t) {
                unsigned short sp8[8];
                #pragma unroll
                for (int j=0;j<8;++j) {
                    float y = Ep[(orow0+j)*132 + t*32 + ns]*BNi[oloc0+j] + BNo[oloc0+j];
                    float h = v[j] + (y - v[j])*0.5f;
                    bool sp = (h - 1.0f) >= 0.f;
                    v[j] = sp ? 0.f : h;
                    sp8[j] = sp ? 0x3F80u : 0u;
                }
                *(uint4*)((unsigned short*)out + (((size_t)(t*B_ + b)*NH_ + hh)*N_ + n)*D_ + dd0)
                    = *(uint4*)sp8;
            }
        }
    }
}

// ------------- K3: fused attention + attn-LIF per (b,h): S2 = LIF_t( Q (K^T V) * 0.125 ) -------------
__global__ __launch_bounds__(256) void k_attn(const __hip_bfloat16* __restrict__ qs,
                                              const __hip_bfloat16* __restrict__ ks,
                                              const __hip_bfloat16* __restrict__ vs,
                                              unsigned short* __restrict__ s2) {
    __shared__ unsigned short Kb[HEADELE];
    __shared__ unsigned short Vb[HEADELE];
    __shared__ float KtV[48][52];
    __shared__ int rowAny[256];
    __shared__ int mcnt;
    __shared__ int mlist[256];
    const int tid = threadIdx.x;
    const int bh = blockIdx.x;                       // b*NH + h

    float vst[48];
    #pragma unroll
    for (int j=0;j<48;++j) vst[j]=0.f;

    for (int t = 0; t < T_; ++t) {
        const size_t base = (size_t)(t*B_*NH_ + bh) * HEADELE;
        rowAny[tid] = 0;
        if (tid == 0) mcnt = 0;
        __syncthreads();

        const uint4* kp = (const uint4*)(ks + base);
        const uint4* vp = (const uint4*)(vs + base);
        unsigned int ka = 0, vaf = 0;
        #pragma unroll
        for (int i=0;i<6;++i) {
            int q = tid + i*256;
            uint4 u = kp[q];
            unsigned int nz = (u.x|u.y|u.z|u.w);
            ka |= nz;
            unsigned short* d = &Kb[q*8];
            d[0]=(unsigned short)(u.x&0xFFFFu); d[1]=(unsigned short)(u.x>>16);
            d[2]=(unsigned short)(u.y&0xFFFFu); d[3]=(unsigned short)(u.y>>16);
            d[4]=(unsigned short)(u.z&0xFFFFu); d[5]=(unsigned short)(u.z>>16);
            d[6]=(unsigned short)(u.w&0xFFFFu); d[7]=(unsigned short)(u.w>>16);
            if (nz) { int m0=(q*8)/D_, m1=(q*8+7)/D_; atomicOr(&rowAny[m0],1); if (m1!=m0) atomicOr(&rowAny[m1],1); }
            uint4 wv = vp[q];
            nz = (wv.x|wv.y|wv.z|wv.w);
            vaf |= nz;
            unsigned short* e = &Vb[q*8];
            e[0]=(unsigned short)(wv.x&0xFFFFu); e[1]=(unsigned short)(wv.x>>16);
            e[2]=(unsigned short)(wv.y&0xFFFFu); e[3]=(unsigned short)(wv.y>>16);
            e[4]=(unsigned short)(wv.z&0xFFFFu); e[5]=(unsigned short)(wv.z>>16);
            e[6]=(unsigned short)(wv.w&0xFFFFu); e[7]=(unsigned short)(wv.w>>16);
            if (nz) { int m0=(q*8)/D_, m1=(q*8+7)/D_; atomicOr(&rowAny[m0],2); if (m1!=m0) atomicOr(&rowAny[m1],2); }
        }
        int flags = __syncthreads_or((ka ? 1 : 0) | (vaf ? 2 : 0));
        float oc[48];
        bool havep = ((flags & 3) == 3);
        if (havep) {
            if (rowAny[tid] == 3) mlist[atomicAdd(&mcnt, 1)] = tid;
            __syncthreads();
            const int dd1 = tid >> 2, gg = tid & 3;
            if (tid < 192) {
                float acc[12];
                #pragma unroll
                for (int i=0;i<12;++i) acc[i]=0.f;
                int cnt = mcnt;
                for (int ii=0; ii<cnt; ++ii) {
                    int m = mlist[ii];
                    if (Kb[m*D_ + dd1] != 0) {
                        const unsigned short* vr = &Vb[m*D_ + gg*12];
                        #pragma unroll
                        for (int i=0;i<12;++i) acc[i] += bf2f(vr[i]);
                    }
                }
                #pragma unroll
                for (int i=0;i<12;++i) KtV[dd1][gg*12+i] = acc[i];
            }
            __syncthreads();

            float qf[48];
            const uint4* qp = (const uint4*)(qs + base + (size_t)tid*D_);
            unsigned int qa = 0;
            #pragma unroll
            for (int i=0;i<6;++i) { uint4 u = qp[i]; qa |= (u.x|u.y|u.z|u.w); unpack8(u, &qf[i*8]); }
            #pragma unroll
            for (int i=0;i<48;++i) oc[i]=0.f;
            if (qa) {
                for (int d1=0; d1<48; ++d1) {
                    if (qf[d1] != 0.f) {
                        const float* kt = &KtV[d1][0];
                        #pragma unroll
                        for (int i=0;i<48;++i) oc[i] += kt[i];
                    }
                }
            }
        } else {
            #pragma unroll
            for (int i=0;i<48;++i) oc[i]=0.f;
        }
        // LIF over t for row n=tid, 48 dd, write spikes
        unsigned short sp[48];
        #pragma unroll
        for (int j=0;j<48;++j) {
            float y = oc[j]*0.125f;
            float h = vst[j] + (y - vst[j])*0.5f;
            bool s = (h - 1.0f) >= 0.f;
            vst[j] = s ? 0.f : h;
            sp[j] = s ? 0x3F80u : 0u;
        }
        unsigned short* op = s2 + base + (size_t)tid*D_;
        #pragma unroll
        for (int i=0;i<6;++i) ((uint4*)op)[i] = ((uint4*)sp)[i];
        __syncthreads();
    }
}

// ---------------- K4: proj MFMA GEMM + bias + BN -> out [T][B][C][N] fp32, LDS-free K-loop ----------------
__global__ __launch_bounds__(256) void k_proj(const unsigned short* __restrict__ s2,
        const unsigned short* __restrict__ Wgh, const unsigned short* __restrict__ Wgl,
        const float* __restrict__ pb,
        const float* __restrict__ g, const float* __restrict__ be,
        const float* __restrict__ me, const float* __restrict__ va,
        float* __restrict__ out) {
    __shared__ float Ep[32*132];
    __shared__ float BNi[128], BNo[128];
    const int tid = threadIdx.x;
    const int o0 = blockIdx.x * 128;
    const int b  = blockIdx.y >> 3;
    const int n0 = (blockIdx.y & 7) * 32;
    const int w    = tid >> 6;
    const int lane = tid & 63;
    const int quad = lane >> 4;
    const int lc   = lane & 15;
    const int mbase = (w >> 1) * 64;
    const int nbase = (w & 1) * 64;

    if (tid < 128) {
        int o = o0 + tid;
        float inv = g[o] / sqrtf(va[o] + 1e-5f);
        BNi[tid] = inv;
        BNo[tid] = be[o] - me[o]*inv + pb[o]*inv;    // bias folded
    }

    const unsigned short* pAh[4];
    const unsigned short* pAl[4];
    const unsigned short* pB[4];
    #pragma unroll
    for (int mt=0;mt<4;++mt) {
        size_t off = (size_t)(o0 + mbase + mt*16 + lc)*C_ + quad*8;
        pAh[mt] = Wgh + off;
        pAl[mt] = Wgl + off;
    }
    #pragma unroll
    for (int nt=0;nt<4;++nt) {
        int col = nbase + nt*16 + lc;
        int t = col >> 5, ns = col & 31;
        // k = quad*8 within [T][B][NH][N][D]: k -> (hh = k/48, dd = k%48), chunks never cross head
        pB[nt] = s2 + (size_t)(t*B_ + b)*NH_*N_*D_ + (size_t)(n0 + ns)*D_;   // + hh*N_*D_ + dd added per step
    }

    f32x4 acc[4][4];
    #pragma unroll
    for (int mt=0;mt<4;++mt)
        #pragma unroll
        for (int nt=0;nt<4;++nt) { acc[mt][nt][0]=0.f; acc[mt][nt][1]=0.f; acc[mt][nt][2]=0.f; acc[mt][nt][3]=0.f; }

    #pragma unroll 2
    for (int ks = 0; ks < 12; ++ks) {
        int k0 = ks*32 + quad*8;
        bf16x8 ah[4], al[4], bb[4];
        #pragma unroll
        for (int mt=0;mt<4;++mt) {
            ah[mt] = *(const bf16x8*)(pAh[mt]);
            al[mt] = *(const bf16x8*)(pAl[mt]);
            pAh[mt] += 32; pAl[mt] += 32;
        }
        int hh = k0 / D_, dd = k0 - hh*D_;
        #pragma unroll
        for (int nt=0;nt<4;++nt)
            bb[nt] = *(const bf16x8*)(pB[nt] + (size_t)hh*N_*D_ + dd);
        #pragma unroll
        for (int mt=0;mt<4;++mt)
            #pragma unroll
            for (int nt=0;nt<4;++nt) {
                acc[mt][nt] = __builtin_amdgcn_mfma_f32_16x16x32_bf16(ah[mt], bb[nt], acc[mt][nt], 0,0,0);
                acc[mt][nt] = __builtin_amdgcn_mfma_f32_16x16x32_bf16(al[mt], bb[nt], acc[mt][nt], 0,0,0);
            }
    }

    for (int r = 0; r < 4; ++r) {
        __syncthreads();
        int erow = (w>>1)*16 + quad*4;
        #pragma unroll
        for (int nt=0;nt<4;++nt) {
            int col = (w&1)*64 + nt*16 + lc;
            Ep[(erow+0)*132 + col] = acc[r][nt][0];
            Ep[(erow+1)*132 + col] = acc[r][nt][1];
            Ep[(erow+2)*132 + col] = acc[r][nt][2];
            Ep[(erow+3)*132 + col] = acc[r][nt][3];
        }
        __syncthreads();
        #pragma unroll
        for (int q=0;q<4;++q) {
            int e = q*256 + tid;                     // 0..1023
            int orow = e >> 5;
            int rem = e & 31;
            int t = rem >> 3, nq = rem & 7;
            int oloc = ((orow & 16) ? 64 : 0) + r*16 + (orow & 15);
            int o = o0 + oloc;
            float4 f = *(const float4*)&Ep[orow*132 + t*32 + nq*4];
            float inv = BNi[oloc], off = BNo[oloc];
            float4 rr = make_float4(f.x*inv+off, f.y*inv+off, f.z*inv+off, f.w*inv+off);
            *(float4*)(out + (((size_t)t*B_ + b)*C_ + o)*N_ + n0 + nq*4) = rr;
        }
    }
}

extern "C" void kernel_launch(void* const* d_in, const int* in_sizes, int n_in,
                              void* d_out, int out_size, void* d_ws, size_t ws_size,
                              hipStream_t stream) {
    const float* x  = (const float*)d_in[0];
    char* ws = (char*)d_ws;
    // ws: S0/S2 [0,25165824) | Q/K/V 3x25165824 | WHI/WLO (4x147456 ushorts each)
    unsigned short* S0 = (unsigned short*)ws;
    __hip_bfloat16* Q  = (__hip_bfloat16*)(ws + 25165824);
    __hip_bfloat16* K  = (__hip_bfloat16*)(ws + 50331648);
    __hip_bfloat16* V  = (__hip_bfloat16*)(ws + 75497472);
    unsigned short* WHI = (unsigned short*)(ws + 100663296);
    unsigned short* WLO = WHI + 4*147456;
    unsigned short* S2 = (unsigned short*)ws;

    k_wsplit<<<dim3(144,4), 256, 0, stream>>>(
        (const float*)d_in[2], (const float*)d_in[7], (const float*)d_in[12],
        (const float*)d_in[17], WHI, WLO);

    k_lif1<<<dim3(32,6,4), 256, 0, stream>>>(x, S0);

    Br2 ba;
    for (int z=0;z<3;++z) { ba.whi[z] = WHI + z*147456; ba.wlo[z] = WLO + z*147456; }
    ba.g[0]=(const float*)d_in[3];  ba.be[0]=(const float*)d_in[4];
    ba.me[0]=(const float*)d_in[5]; ba.va[0]=(const float*)d_in[6];
    ba.g[1]=(const float*)d_in[8];  ba.be[1]=(const float*)d_in[9];
    ba.me[1]=(const float*)d_in[10]; ba.va[1]=(const float*)d_in[11];
    ba.g[2]=(const float*)d_in[13]; ba.be[2]=(const float*)d_in[14];
    ba.me[2]=(const float*)d_in[15]; ba.va[2]=(const float*)d_in[16];
    ba.out[0]=Q; ba.out[1]=K; ba.out[2]=V;
    k_branch<<<dim3(3, 256, 3), 256, 0, stream>>>(S0, ba);

    k_attn<<<B_*NH_, 256, 0, stream>>>(Q, K, V, S2);

    k_proj<<<dim3(3, 256), 256, 0, stream>>>(S2,
        WHI + 3*147456, WLO + 3*147456,
        (const float*)d_in[18],
        (const float*)d_in[19], (const float*)d_in[20],
        (const float*)d_in[21], (const float*)d_in[22],
        (float*)d_out);
}

// Round 4
// 281.128 us; speedup vs baseline: 1.3737x; 1.3737x over previous
//
#include <hip/hip_runtime.h>
#include <hip/hip_bf16.h>

// SpikingSelfAttention: T=4 B=32 C=384 N=256 NH=8 D=48
#define T_  4
#define B_  32
#define C_  384
#define N_  256
#define NH_ 8
#define D_  48
#define HEADELE (N_*D_)      // 12288 elements per (t,b,h)

typedef __attribute__((ext_vector_type(8))) short bf16x8;
typedef __attribute__((ext_vector_type(4))) float f32x4;

__device__ __forceinline__ float bf2f(unsigned short s) {
    return __uint_as_float(((unsigned int)s) << 16);
}
__device__ __forceinline__ unsigned short f2bf(float f) {
    __hip_bfloat16 h = __float2bfloat16(f);
    return __builtin_bit_cast(unsigned short, h);
}
__device__ __forceinline__ void unpack8(uint4 u, float* d) {
    d[0]=__uint_as_float((u.x&0xFFFFu)<<16); d[1]=__uint_as_float(u.x&0xFFFF0000u);
    d[2]=__uint_as_float((u.y&0xFFFFu)<<16); d[3]=__uint_as_float(u.y&0xFFFF0000u);
    d[4]=__uint_as_float((u.z&0xFFFFu)<<16); d[5]=__uint_as_float(u.z&0xFFFF0000u);
    d[6]=__uint_as_float((u.w&0xFFFFu)<<16); d[7]=__uint_as_float(u.w&0xFFFF0000u);
}

// ---- K0: split fp32 weights into hi/lo bf16, FRAGMENT-MAJOR [otile24][ks12][lane64][8] ----
__global__ __launch_bounds__(256) void k_wsplit(const float* __restrict__ w0,
                                                const float* __restrict__ w1,
                                                const float* __restrict__ w2,
                                                const float* __restrict__ w3,
                                                unsigned short* __restrict__ hi,
                                                unsigned short* __restrict__ lo) {
    const float* w = (blockIdx.y==0) ? w0 : (blockIdx.y==1) ? w1 : (blockIdx.y==2) ? w2 : w3;
    int g = blockIdx.x*256 + threadIdx.x;            // 0..18431 (72 blocks)
    int otile = g / 768;
    int rem = g - otile*768;
    int lane = rem & 63;
    int o  = otile*16 + (lane & 15);
    int k0 = (rem >> 6)*32 + (lane >> 4)*8;
    const float* src = w + (size_t)o*C_ + k0;
    unsigned short h8[8], l8[8];
    #pragma unroll
    for (int j=0;j<8;++j) {
        float f = src[j];
        h8[j] = f2bf(f);
        l8[j] = f2bf(f - bf2f(h8[j]));
    }
    size_t dst = (size_t)blockIdx.y*147456 + (size_t)g*8;
    *(uint4*)(hi + dst) = *(uint4*)h8;
    *(uint4*)(lo + dst) = *(uint4*)l8;
}

// ---- K1: LIF over T on x; spikes bf16 FRAGMENT-MAJOR: [t][b][ntile16][ks12][lane64][8] ----
__global__ __launch_bounds__(256) void k_lif1(const float* __restrict__ x,
                                              unsigned short* __restrict__ s0) {
    __shared__ unsigned short Tt[64*72];             // [n_local][c_local], padded row 72
    const int tid = threadIdx.x;
    const int b  = blockIdx.x;
    const int c0 = blockIdx.y * 64;
    const int n0 = blockIdx.z * 64;
    const int ci = tid >> 2;
    const int nj = (tid & 3) * 16;
    float v[16];
    #pragma unroll
    for (int i=0;i<16;++i) v[i]=0.f;
    for (int t = 0; t < T_; ++t) {
        const float* xp = x + (((size_t)t*B_ + b)*C_ + c0 + ci)*N_ + n0 + nj;
        #pragma unroll
        for (int q=0;q<4;++q) {
            float4 f = *(const float4*)(xp + q*4);
            float e[4] = {f.x,f.y,f.z,f.w};
            #pragma unroll
            for (int j=0;j<4;++j) {
                int ii = q*4+j;
                float h = v[ii] + (e[j] - v[ii])*0.5f;
                bool sp = (h - 1.0f) >= 0.f;
                v[ii] = sp ? 0.f : h;
                Tt[(nj + ii)*72 + ci] = sp ? 0x3F80u : 0u;
            }
        }
        __syncthreads();
        int nrow = tid >> 2, cch = (tid & 3)*16;
        int n = n0 + nrow;
        uint4 u0 = *(const uint4*)&Tt[nrow*72 + cch];
        uint4 u1 = *(const uint4*)&Tt[nrow*72 + cch + 8];
        size_t tb16 = ((size_t)(t*B_ + b)*16 + (n>>4))*12;
        int c8a = c0 + cch, c8b = c0 + cch + 8;
        *(uint4*)(s0 + (tb16 + (c8a>>5))*512 + (((c8a>>3)&3)*16 + (n&15))*8) = u0;
        *(uint4*)(s0 + (tb16 + (c8b>>5))*512 + (((c8b>>3)&3)*16 + (n&15))*8) = u1;
        __syncthreads();
    }
}

// ------------- K2: MFMA branch GEMM, fragment-major coalesced loads, no LDS operands -------------
struct Br2 {
    const unsigned short* whi[3];
    const unsigned short* wlo[3];
    const float *g[3], *be[3], *me[3], *va[3];
    __hip_bfloat16* out[3];
};

__global__ __launch_bounds__(256, 2) void k_branch(const unsigned short* __restrict__ s0, Br2 a) {
    __shared__ float Ep[32*132];
    __shared__ float BNi[128], BNo[128];
    const int tid = threadIdx.x;
    const int z  = blockIdx.z;
    const int o0 = blockIdx.x * 128;
    const int b  = blockIdx.y >> 3;
    const int n0 = (blockIdx.y & 7) * 32;
    const int w    = tid >> 6;
    const int lane = tid & 63;
    const int quad = lane >> 4;
    const int lc   = lane & 15;
    const unsigned short* __restrict__ Wgh = a.whi[z];
    const unsigned short* __restrict__ Wgl = a.wlo[z];

    if (tid < 128) {
        int o = o0 + tid;
        float inv = a.g[z][o] / sqrtf(a.va[z][o] + 1e-5f);
        BNi[tid] = inv;
        BNo[tid] = a.be[z][o] - a.me[z][o]*inv;
    }

    const int base_ot = (o0 >> 4) + (w >> 1)*4;
    const unsigned short* pAh[4];
    const unsigned short* pAl[4];
    const unsigned short* pB[4];
    #pragma unroll
    for (int mt=0;mt<4;++mt) {
        size_t off = (size_t)(base_ot + mt)*6144 + lane*8;
        pAh[mt] = Wgh + off;
        pAl[mt] = Wgl + off;
    }
    #pragma unroll
    for (int nt=0;nt<4;++nt) {
        int colb = (w&1)*64 + nt*16;
        int t = colb >> 5;
        int ntile = (n0 >> 4) + ((colb & 31) >> 4);
        pB[nt] = s0 + ((size_t)(t*B_ + b)*16 + ntile)*6144 + lane*8;
    }

    f32x4 acc[4][4];
    #pragma unroll
    for (int mt=0;mt<4;++mt)
        #pragma unroll
        for (int nt=0;nt<4;++nt) { acc[mt][nt][0]=0.f; acc[mt][nt][1]=0.f; acc[mt][nt][2]=0.f; acc[mt][nt][3]=0.f; }

    bf16x8 cah[4], cal[4], cbb[4];
    #pragma unroll
    for (int mt=0;mt<4;++mt) {
        cah[mt] = *(const bf16x8*)(pAh[mt]); pAh[mt] += 512;
        cal[mt] = *(const bf16x8*)(pAl[mt]); pAl[mt] += 512;
    }
    #pragma unroll
    for (int nt=0;nt<4;++nt) { cbb[nt] = *(const bf16x8*)(pB[nt]); pB[nt] += 512; }

    #pragma unroll
    for (int ks = 0; ks < 12; ++ks) {
        bf16x8 nah[4], nal[4], nbb[4];
        if (ks < 11) {
            #pragma unroll
            for (int mt=0;mt<4;++mt) {
                nah[mt] = *(const bf16x8*)(pAh[mt]); pAh[mt] += 512;
                nal[mt] = *(const bf16x8*)(pAl[mt]); pAl[mt] += 512;
            }
            #pragma unroll
            for (int nt=0;nt<4;++nt) { nbb[nt] = *(const bf16x8*)(pB[nt]); pB[nt] += 512; }
        }
        #pragma unroll
        for (int mt=0;mt<4;++mt)
            #pragma unroll
            for (int nt=0;nt<4;++nt) {
                acc[mt][nt] = __builtin_amdgcn_mfma_f32_16x16x32_bf16(cah[mt], cbb[nt], acc[mt][nt], 0,0,0);
                acc[mt][nt] = __builtin_amdgcn_mfma_f32_16x16x32_bf16(cal[mt], cbb[nt], acc[mt][nt], 0,0,0);
            }
        if (ks < 11) {
            #pragma unroll
            for (int mt=0;mt<4;++mt) { cah[mt]=nah[mt]; cal[mt]=nal[mt]; }
            #pragma unroll
            for (int nt=0;nt<4;++nt) cbb[nt]=nbb[nt];
        }
    }

    // epilogue: 4 rounds; LIF over t + 8-wide spike stores to [t][b][h][n][d]
    __hip_bfloat16* out = a.out[z];
    for (int r = 0; r < 4; ++r) {
        __syncthreads();
        int erow = (w>>1)*16 + quad*4;
        #pragma unroll
        for (int nt=0;nt<4;++nt) {
            int col = (w&1)*64 + nt*16 + lc;
            Ep[(erow+0)*132 + col] = acc[r][nt][0];
            Ep[(erow+1)*132 + col] = acc[r][nt][1];
            Ep[(erow+2)*132 + col] = acc[r][nt][2];
            Ep[(erow+3)*132 + col] = acc[r][nt][3];
        }
        __syncthreads();
        if (tid < 128) {
            int ns = tid & 31, oct = tid >> 5;
            int orow0 = oct*8;
            int oloc0 = ((orow0 & 16) ? 64 : 0) + r*16 + (orow0 & 15);
            int og = o0 + oloc0;
            int hh = og / D_, dd0 = og - hh*D_;
            int n = n0 + ns;
            float v[8];
            #pragma unroll
            for (int j=0;j<8;++j) v[j]=0.f;
            #pragma unroll
            for (int t=0;t<4;++t) {
                unsigned short sp8[8];
                #pragma unroll
                for (int j=0;j<8;++j) {
                    float y = Ep[(orow0+j)*132 + t*32 + ns]*BNi[oloc0+j] + BNo[oloc0+j];
                    float h = v[j] + (y - v[j])*0.5f;
                    bool sp = (h - 1.0f) >= 0.f;
                    v[j] = sp ? 0.f : h;
                    sp8[j] = sp ? 0x3F80u : 0u;
                }
                *(uint4*)((unsigned short*)out + (((size_t)(t*B_ + b)*NH_ + hh)*N_ + n)*D_ + dd0)
                    = *(uint4*)sp8;
            }
        }
    }
}

// ------------- K3: fused attention + attn-LIF; S2 written FRAGMENT-MAJOR for proj -------------
__global__ __launch_bounds__(256) void k_attn(const __hip_bfloat16* __restrict__ qs,
                                              const __hip_bfloat16* __restrict__ ks,
                                              const __hip_bfloat16* __restrict__ vs,
                                              unsigned short* __restrict__ s2) {
    __shared__ unsigned short Kb[HEADELE];
    __shared__ unsigned short Vb[HEADELE];
    __shared__ float KtV[48][52];
    __shared__ int rowAny[256];
    __shared__ int mcnt;
    __shared__ int mlist[256];
    const int tid = threadIdx.x;
    const int bh = blockIdx.x;                       // b*NH + h
    const int b2 = bh >> 3, hh = bh & 7;

    float vst[48];
    #pragma unroll
    for (int j=0;j<48;++j) vst[j]=0.f;

    for (int t = 0; t < T_; ++t) {
        const size_t base = (size_t)(t*B_*NH_ + bh) * HEADELE;
        rowAny[tid] = 0;
        if (tid == 0) mcnt = 0;
        __syncthreads();

        const uint4* kp = (const uint4*)(ks + base);
        const uint4* vp = (const uint4*)(vs + base);
        unsigned int ka = 0, vaf = 0;
        #pragma unroll
        for (int i=0;i<6;++i) {
            int q = tid + i*256;
            uint4 u = kp[q];
            unsigned int nz = (u.x|u.y|u.z|u.w);
            ka |= nz;
            unsigned short* d = &Kb[q*8];
            d[0]=(unsigned short)(u.x&0xFFFFu); d[1]=(unsigned short)(u.x>>16);
            d[2]=(unsigned short)(u.y&0xFFFFu); d[3]=(unsigned short)(u.y>>16);
            d[4]=(unsigned short)(u.z&0xFFFFu); d[5]=(unsigned short)(u.z>>16);
            d[6]=(unsigned short)(u.w&0xFFFFu); d[7]=(unsigned short)(u.w>>16);
            if (nz) { int m0=(q*8)/D_, m1=(q*8+7)/D_; atomicOr(&rowAny[m0],1); if (m1!=m0) atomicOr(&rowAny[m1],1); }
            uint4 wv = vp[q];
            nz = (wv.x|wv.y|wv.z|wv.w);
            vaf |= nz;
            unsigned short* e = &Vb[q*8];
            e[0]=(unsigned short)(wv.x&0xFFFFu); e[1]=(unsigned short)(wv.x>>16);
            e[2]=(unsigned short)(wv.y&0xFFFFu); e[3]=(unsigned short)(wv.y>>16);
            e[4]=(unsigned short)(wv.z&0xFFFFu); e[5]=(unsigned short)(wv.z>>16);
            e[6]=(unsigned short)(wv.w&0xFFFFu); e[7]=(unsigned short)(wv.w>>16);
            if (nz) { int m0=(q*8)/D_, m1=(q*8+7)/D_; atomicOr(&rowAny[m0],2); if (m1!=m0) atomicOr(&rowAny[m1],2); }
        }
        int flags = __syncthreads_or((ka ? 1 : 0) | (vaf ? 2 : 0));
        float oc[48];
        bool havep = ((flags & 3) == 3);
        if (havep) {
            if (rowAny[tid] == 3) mlist[atomicAdd(&mcnt, 1)] = tid;
            __syncthreads();
            const int dd1 = tid >> 2, gg = tid & 3;
            if (tid < 192) {
                float acc[12];
                #pragma unroll
                for (int i=0;i<12;++i) acc[i]=0.f;
                int cnt = mcnt;
                for (int ii=0; ii<cnt; ++ii) {
                    int m = mlist[ii];
                    if (Kb[m*D_ + dd1] != 0) {
                        const unsigned short* vr = &Vb[m*D_ + gg*12];
                        #pragma unroll
                        for (int i=0;i<12;++i) acc[i] += bf2f(vr[i]);
                    }
                }
                #pragma unroll
                for (int i=0;i<12;++i) KtV[dd1][gg*12+i] = acc[i];
            }
            __syncthreads();

            float qf[48];
            const uint4* qp = (const uint4*)(qs + base + (size_t)tid*D_);
            unsigned int qa = 0;
            #pragma unroll
            for (int i=0;i<6;++i) { uint4 u = qp[i]; qa |= (u.x|u.y|u.z|u.w); unpack8(u, &qf[i*8]); }
            #pragma unroll
            for (int i=0;i<48;++i) oc[i]=0.f;
            if (qa) {
                for (int d1=0; d1<48; ++d1) {
                    if (qf[d1] != 0.f) {
                        const float* kt = &KtV[d1][0];
                        #pragma unroll
                        for (int i=0;i<48;++i) oc[i] += kt[i];
                    }
                }
            }
        } else {
            #pragma unroll
            for (int i=0;i<48;++i) oc[i]=0.f;
        }
        // LIF over t for row n=tid; store fragment-major: channel k = hh*48 + c8*8 + j
        unsigned short sp[48];
        #pragma unroll
        for (int j=0;j<48;++j) {
            float y = oc[j]*0.125f;
            float h = vst[j] + (y - vst[j])*0.5f;
            bool s = (h - 1.0f) >= 0.f;
            vst[j] = s ? 0.f : h;
            sp[j] = s ? 0x3F80u : 0u;
        }
        size_t tb16 = ((size_t)(t*B_ + b2)*16 + (tid>>4))*12;
        #pragma unroll
        for (int c8=0; c8<6; ++c8) {
            int ci = hh*6 + c8;
            size_t dst = (tb16 + (ci>>2))*512 + (size_t)(((ci&3)*16 + (tid&15))*8);
            *(uint4*)(s2 + dst) = ((uint4*)sp)[c8];
        }
        __syncthreads();
    }
}

// ---- K4: proj MFMA GEMM + bias + BN -> out [T][B][C][N] fp32, fragment-major loads ----
__global__ __launch_bounds__(256, 2) void k_proj(const unsigned short* __restrict__ s2,
        const unsigned short* __restrict__ Wgh, const unsigned short* __restrict__ Wgl,
        const float* __restrict__ pb,
        const float* __restrict__ g, const float* __restrict__ be,
        const float* __restrict__ me, const float* __restrict__ va,
        float* __restrict__ out) {
    __shared__ float Ep[32*132];
    __shared__ float BNi[128], BNo[128];
    const int tid = threadIdx.x;
    const int o0 = blockIdx.x * 128;
    const int b  = blockIdx.y >> 3;
    const int n0 = (blockIdx.y & 7) * 32;
    const int w    = tid >> 6;
    const int lane = tid & 63;
    const int quad = lane >> 4;
    const int lc   = lane & 15;

    if (tid < 128) {
        int o = o0 + tid;
        float inv = g[o] / sqrtf(va[o] + 1e-5f);
        BNi[tid] = inv;
        BNo[tid] = be[o] - me[o]*inv + pb[o]*inv;    // bias folded
    }

    const int base_ot = (o0 >> 4) + (w >> 1)*4;
    const unsigned short* pAh[4];
    const unsigned short* pAl[4];
    const unsigned short* pB[4];
    #pragma unroll
    for (int mt=0;mt<4;++mt) {
        size_t off = (size_t)(base_ot + mt)*6144 + lane*8;
        pAh[mt] = Wgh + off;
        pAl[mt] = Wgl + off;
    }
    #pragma unroll
    for (int nt=0;nt<4;++nt) {
        int colb = (w&1)*64 + nt*16;
        int t = colb >> 5;
        int ntile = (n0 >> 4) + ((colb & 31) >> 4);
        pB[nt] = s2 + ((size_t)(t*B_ + b)*16 + ntile)*6144 + lane*8;
    }

    f32x4 acc[4][4];
    #pragma unroll
    for (int mt=0;mt<4;++mt)
        #pragma unroll
        for (int nt=0;nt<4;++nt) { acc[mt][nt][0]=0.f; acc[mt][nt][1]=0.f; acc[mt][nt][2]=0.f; acc[mt][nt][3]=0.f; }

    bf16x8 cah[4], cal[4], cbb[4];
    #pragma unroll
    for (int mt=0;mt<4;++mt) {
        cah[mt] = *(const bf16x8*)(pAh[mt]); pAh[mt] += 512;
        cal[mt] = *(const bf16x8*)(pAl[mt]); pAl[mt] += 512;
    }
    #pragma unroll
    for (int nt=0;nt<4;++nt) { cbb[nt] = *(const bf16x8*)(pB[nt]); pB[nt] += 512; }

    #pragma unroll
    for (int ks = 0; ks < 12; ++ks) {
        bf16x8 nah[4], nal[4], nbb[4];
        if (ks < 11) {
            #pragma unroll
            for (int mt=0;mt<4;++mt) {
                nah[mt] = *(const bf16x8*)(pAh[mt]); pAh[mt] += 512;
                nal[mt] = *(const bf16x8*)(pAl[mt]); pAl[mt] += 512;
            }
            #pragma unroll
            for (int nt=0;nt<4;++nt) { nbb[nt] = *(const bf16x8*)(pB[nt]); pB[nt] += 512; }
        }
        #pragma unroll
        for (int mt=0;mt<4;++mt)
            #pragma unroll
            for (int nt=0;nt<4;++nt) {
                acc[mt][nt] = __builtin_amdgcn_mfma_f32_16x16x32_bf16(cah[mt], cbb[nt], acc[mt][nt], 0,0,0);
                acc[mt][nt] = __builtin_amdgcn_mfma_f32_16x16x32_bf16(cal[mt], cbb[nt], acc[mt][nt], 0,0,0);
            }
        if (ks < 11) {
            #pragma unroll
            for (int mt=0;mt<4;++mt) { cah[mt]=nah[mt]; cal[mt]=nal[mt]; }
            #pragma unroll
            for (int nt=0;nt<4;++nt) cbb[nt]=nbb[nt];
        }
    }

    for (int r = 0; r < 4; ++r) {
        __syncthreads();
        int erow = (w>>1)*16 + quad*4;
        #pragma unroll
        for (int nt=0;nt<4;++nt) {
            int col = (w&1)*64 + nt*16 + lc;
            Ep[(erow+0)*132 + col] = acc[r][nt][0];
            Ep[(erow+1)*132 + col] = acc[r][nt][1];
            Ep[(erow+2)*132 + col] = acc[r][nt][2];
            Ep[(erow+3)*132 + col] = acc[r][nt][3];
        }
        __syncthreads();
        #pragma unroll
        for (int q=0;q<4;++q) {
            int e = q*256 + tid;
            int orow = e >> 5;
            int rem = e & 31;
            int t = rem >> 3, nq = rem & 7;
            int oloc = ((orow & 16) ? 64 : 0) + r*16 + (orow & 15);
            int o = o0 + oloc;
            float4 f = *(const float4*)&Ep[orow*132 + t*32 + nq*4];
            float inv = BNi[oloc], off = BNo[oloc];
            float4 rr = make_float4(f.x*inv+off, f.y*inv+off, f.z*inv+off, f.w*inv+off);
            *(float4*)(out + (((size_t)t*B_ + b)*C_ + o)*N_ + n0 + nq*4) = rr;
        }
    }
}

extern "C" void kernel_launch(void* const* d_in, const int* in_sizes, int n_in,
                              void* d_out, int out_size, void* d_ws, size_t ws_size,
                              hipStream_t stream) {
    const float* x  = (const float*)d_in[0];
    char* ws = (char*)d_ws;
    unsigned short* S0 = (unsigned short*)ws;
    __hip_bfloat16* Q  = (__hip_bfloat16*)(ws + 25165824);
    __hip_bfloat16* K  = (__hip_bfloat16*)(ws + 50331648);
    __hip_bfloat16* V  = (__hip_bfloat16*)(ws + 75497472);
    unsigned short* WHI = (unsigned short*)(ws + 100663296);
    unsigned short* WLO = WHI + 4*147456;
    unsigned short* S2 = (unsigned short*)ws;

    k_wsplit<<<dim3(72,4), 256, 0, stream>>>(
        (const float*)d_in[2], (const float*)d_in[7], (const float*)d_in[12],
        (const float*)d_in[17], WHI, WLO);

    k_lif1<<<dim3(32,6,4), 256, 0, stream>>>(x, S0);

    Br2 ba;
    for (int z=0;z<3;++z) { ba.whi[z] = WHI + z*147456; ba.wlo[z] = WLO + z*147456; }
    ba.g[0]=(const float*)d_in[3];  ba.be[0]=(const float*)d_in[4];
    ba.me[0]=(const float*)d_in[5]; ba.va[0]=(const float*)d_in[6];
    ba.g[1]=(const float*)d_in[8];  ba.be[1]=(const float*)d_in[9];
    ba.me[1]=(const float*)d_in[10]; ba.va[1]=(const float*)d_in[11];
    ba.g[2]=(const float*)d_in[13]; ba.be[2]=(const float*)d_in[14];
    ba.me[2]=(const float*)d_in[15]; ba.va[2]=(const float*)d_in[16];
    ba.out[0]=Q; ba.out[1]=K; ba.out[2]=V;
    k_branch<<<dim3(3, 256, 3), 256, 0, stream>>>(S0, ba);

    k_attn<<<B_*NH_, 256, 0, stream>>>(Q, K, V, S2);

    k_proj<<<dim3(3, 256), 256, 0, stream>>>(S2,
        WHI + 3*147456, WLO + 3*147456,
        (const float*)d_in[18],
        (const float*)d_in[19], (const float*)d_in[20],
        (const float*)d_in[21], (const float*)d_in[22],
        (float*)d_out);
}